// Round 1
// baseline (342.330 us; speedup 1.0000x reference)
//
#include <hip/hip_runtime.h>

// MMD loss, fused. z = [xf; yf] (8192 x 256). Result = (1/4096^2) * sum_{ij} s_i s_j k(z_i,z_j)
// with s = +1 for x rows, -1 for y rows. Symmetric => upper-triangular tiles only.
//
// ws layout: [0, 32768) float norms[8192]; [32768, 32776) double acc.

#define C_DIM 256
#define HW    1024          // H*W = 32*32
#define N_HALF 4096         // B*H*W
#define N_ROWS 8192
#define TI    128           // tile size (rows i and j)
#define BK    32            // K-chunk
#define NT    (N_ROWS / TI) // 64 tiles per side
#define NSIG  5

__global__ void norms_kernel(const float* __restrict__ x,
                             const float* __restrict__ y,
                             float* __restrict__ norms,
                             double* __restrict__ acc) {
    int n = blockIdx.x * blockDim.x + threadIdx.x;   // 0..8191
    if (n == 0) *acc = 0.0;                          // zero the accumulator (stream-ordered before tiles)
    if (n >= N_ROWS) return;
    const float* src = (n < N_HALF) ? x : y;
    int m = n & (N_HALF - 1);
    int b = m >> 10;          // / HW
    int p = m & (HW - 1);
    const float* row = src + (size_t)b * (C_DIM * HW) + p;
    float s = 0.f;
#pragma unroll 8
    for (int c = 0; c < C_DIM; ++c) {
        float v = row[(size_t)c * HW];
        s = fmaf(v, v, s);
    }
    norms[n] = s;
}

__global__ __launch_bounds__(256)
void mmd_tiles(const float* __restrict__ x,
               const float* __restrict__ y,
               const float* __restrict__ norms,
               const float* __restrict__ sigmas,
               double* __restrict__ acc) {
    const int bi = blockIdx.y;
    const int bj = blockIdx.x;
    if (bj < bi) return;                      // upper triangle only

    __shared__ float As[BK][TI];
    __shared__ float Bs[BK][TI];
    __shared__ float wsum[4];

    const int t  = threadIdx.x;
    const int tx = t & 15;
    const int ty = t >> 4;

    const int i0 = bi * TI;
    const int j0 = bj * TI;

    // Tile row base pointers. 128-row tiles never cross a batch (1024) boundary.
    const float* srcA = (i0 < N_HALF) ? x : y;
    const int mi = i0 & (N_HALF - 1);
    const float* baseA = srcA + (size_t)(mi >> 10) * (C_DIM * HW) + (mi & (HW - 1));
    const float* srcB = (j0 < N_HALF) ? x : y;
    const int mj = j0 & (N_HALF - 1);
    const float* baseB = srcB + (size_t)(mj >> 10) * (C_DIM * HW) + (mj & (HW - 1));

    float accv[8][8];
#pragma unroll
    for (int r = 0; r < 8; ++r)
#pragma unroll
        for (int s = 0; s < 8; ++s) accv[r][s] = 0.f;

    for (int k0 = 0; k0 < C_DIM; k0 += BK) {
        __syncthreads();
        // Stage A and B tiles: [BK][TI] floats each, 1024 float4 per tile, 4 per thread.
#pragma unroll
        for (int r = 0; r < 4; ++r) {
            int q = t + r * 256;        // 0..1023
            int k = q >> 5;             // 0..31
            int f = (q & 31) << 2;      // float offset 0..124
            float4 av = *(const float4*)(baseA + (size_t)(k0 + k) * HW + f);
            *(float4*)(&As[k][f]) = av;
            float4 bv = *(const float4*)(baseB + (size_t)(k0 + k) * HW + f);
            *(float4*)(&Bs[k][f]) = bv;
        }
        __syncthreads();
#pragma unroll
        for (int k = 0; k < BK; ++k) {
            float a0[8], b0[8];
            // micro-tile rows: {tx*4..+3} and {64+tx*4..+3} -> conflict-free b128 reads
            *(float4*)&a0[0] = *(const float4*)&As[k][tx * 4];
            *(float4*)&a0[4] = *(const float4*)&As[k][64 + tx * 4];
            *(float4*)&b0[0] = *(const float4*)&Bs[k][ty * 4];
            *(float4*)&b0[4] = *(const float4*)&Bs[k][64 + ty * 4];
#pragma unroll
            for (int r = 0; r < 8; ++r)
#pragma unroll
                for (int s = 0; s < 8; ++s)
                    accv[r][s] = fmaf(a0[r], b0[s], accv[r][s]);
        }
    }

    // Epilogue
    float beta[NSIG];
#pragma unroll
    for (int k = 0; k < NSIG; ++k) beta[k] = 0.5f / sigmas[k];

    const float sgn = ((i0 < N_HALF) == (j0 < N_HALF)) ? 1.f : -1.f;

    int iofs[8], jofs[8];
#pragma unroll
    for (int r = 0; r < 4; ++r) { iofs[r] = tx * 4 + r; iofs[r + 4] = 64 + tx * 4 + r; }
#pragma unroll
    for (int s = 0; s < 4; ++s) { jofs[s] = ty * 4 + s; jofs[s + 4] = 64 + ty * 4 + s; }

    float ni[8], nj[8];
#pragma unroll
    for (int r = 0; r < 8; ++r) ni[r] = norms[i0 + iofs[r]];
#pragma unroll
    for (int s = 0; s < 8; ++s) nj[s] = norms[j0 + jofs[s]];

    float lsum = 0.f;
#pragma unroll
    for (int r = 0; r < 8; ++r) {
#pragma unroll
        for (int s = 0; s < 8; ++s) {
            int gi = i0 + iofs[r];
            int gj = j0 + jofs[s];
            // weight: diagonal 1 (d forced to 0), upper 2, lower 0 (only occurs in diagonal blocks)
            float w = (gi == gj) ? 1.f : (gi < gj ? 2.f : 0.f);
            float d = ni[r] + nj[s] - 2.f * accv[r][s];
            d = fmaxf(d, 0.f);
            if (gi == gj) d = 0.f;      // exact: sum_k exp(0) = K
            float ks = 0.f;
#pragma unroll
            for (int k = 0; k < NSIG; ++k) ks += __expf(-beta[k] * d);
            lsum = fmaf(w, ks, lsum);
        }
    }
    lsum *= sgn;

    // block reduction: wave shuffle then cross-wave via LDS
#pragma unroll
    for (int off = 32; off > 0; off >>= 1) lsum += __shfl_down(lsum, off, 64);
    if ((t & 63) == 0) wsum[t >> 6] = lsum;
    __syncthreads();
    if (t == 0) {
        float s = wsum[0] + wsum[1] + wsum[2] + wsum[3];
        atomicAdd(acc, (double)s);
    }
}

__global__ void finalize_kernel(const double* __restrict__ acc, float* __restrict__ out) {
    out[0] = (float)(*acc * (1.0 / ((double)N_HALF * (double)N_HALF)));
}

extern "C" void kernel_launch(void* const* d_in, const int* in_sizes, int n_in,
                              void* d_out, int out_size, void* d_ws, size_t ws_size,
                              hipStream_t stream) {
    const float* x   = (const float*)d_in[0];
    const float* y   = (const float*)d_in[1];
    const float* sig = (const float*)d_in[2];
    float*  norms = (float*)d_ws;
    double* acc   = (double*)((char*)d_ws + N_ROWS * sizeof(float));
    float*  out   = (float*)d_out;

    norms_kernel<<<N_ROWS / 256, 256, 0, stream>>>(x, y, norms, acc);
    dim3 grid(NT, NT);
    mmd_tiles<<<grid, 256, 0, stream>>>(x, y, norms, sig, acc);
    finalize_kernel<<<1, 1, 0, stream>>>(acc, out);
}

// Round 2
// 131.879 us; speedup vs baseline: 2.5958x; 2.5958x over previous
//
#include <hip/hip_runtime.h>
#include <hip/hip_bf16.h>

// MMD loss via bf16 MFMA Gram matrix.
// z = [xf; yf] (8192 x 256). result = (1/4096^2) * sum_ij s_i s_j sum_k exp(-beta_k * d_ij)
// Symmetric => linearized upper-triangular 128x128 tiles (2080 blocks).
//
// ws layout: [0, 4MiB) bf16 Z[8192][256]; [4MiB, +32KiB) float norms[8192]; then double acc.

#define NSIG 5
#define NT   64          // 8192 / 128 tiles per side
#define NBLK ((NT * (NT + 1)) / 2)   // 2080

typedef __attribute__((ext_vector_type(8))) short short8;
typedef __attribute__((ext_vector_type(4))) float floatx4;

__device__ __forceinline__ void glds16(const ushort* g, ushort* l) {
    __builtin_amdgcn_global_load_lds((const __attribute__((address_space(1))) void*)g,
                                     (__attribute__((address_space(3))) void*)l,
                                     16, 0, 0);
}

// ---- prep: (B,C,H,W) fp32 -> Z[n][c] bf16 row-major, fused norms (fp32 sums of bf16^2), zero acc ----
__global__ __launch_bounds__(256) void prep_kernel(const float* __restrict__ x,
                                                   const float* __restrict__ y,
                                                   __hip_bfloat16* __restrict__ Z,
                                                   float* __restrict__ norms,
                                                   double* __restrict__ acc) {
    const int bid = blockIdx.x;            // 0..255: s(1b) | b(2b) | pstrip(5b)
    if (bid == 0 && threadIdx.x == 0) *acc = 0.0;
    const int s = bid >> 7;
    const int rem = bid & 127;
    const int b = rem >> 5;
    const int p0 = (rem & 31) << 5;
    const float* src = s ? y : x;
    const int n0 = s * 4096 + b * 1024 + p0;

    __shared__ float tile[32][33];
    __shared__ float nacc[32];
    const int t = threadIdx.x;
    const int tx = t & 31, ty = t >> 5;
    if (t < 32) nacc[t] = 0.f;
    __syncthreads();

    for (int pass = 0; pass < 8; ++pass) {
        const int c0 = pass << 5;
#pragma unroll
        for (int i = 0; i < 4; ++i) {
            const int cc = ty + (i << 3);                  // c - c0
            tile[cc][tx] = src[(size_t)((b << 8) + c0 + cc) * 1024 + p0 + tx];
        }
        __syncthreads();
#pragma unroll
        for (int i = 0; i < 4; ++i) {
            const int prow = ty + (i << 3);
            const float v = tile[tx][prow];                // (c=c0+tx, p=p0+prow)
            const __hip_bfloat16 hv = __float2bfloat16(v);
            Z[(size_t)(n0 + prow) * 256 + c0 + tx] = hv;
            float q = __bfloat162float(hv);
            float sq = q * q;                              // norms from bf16 (consistent with dots)
#pragma unroll
            for (int off = 16; off > 0; off >>= 1) sq += __shfl_down(sq, off, 32);
            if (tx == 0) nacc[prow] += sq;
        }
        __syncthreads();
    }
    if (t < 32) norms[n0 + t] = nacc[t];
}

// ---- GEMM (bf16 MFMA) + fused MMD epilogue ----
__global__ __launch_bounds__(256) void gemm_epi(const ushort* __restrict__ Z,
                                                const float* __restrict__ norms,
                                                const float* __restrict__ sigmas,
                                                double* __restrict__ acc) {
    __shared__ ushort lA[128 * 32];
    __shared__ ushort lB[128 * 32];
    __shared__ float wsum[4];

    // decode linear block id -> (bi, bj), bi <= bj
    const int L = blockIdx.x;
#define TRI(b) ((b) * NT - ((b) * ((b) - 1)) / 2)
    int bi = (int)((129.0f - sqrtf((float)(129 * 129 - 8 * L))) * 0.5f);
    if (bi < 0) bi = 0;
    if (bi > NT - 1) bi = NT - 1;
    while (TRI(bi + 1) <= L) ++bi;
    while (TRI(bi) > L) --bi;
    const int bj = bi + (L - TRI(bi));

    const int i0 = bi << 7, j0 = bj << 7;
    const int t = threadIdx.x;
    const int w = t >> 6, l = t & 63;
    const int wi = w >> 1, wj = w & 1;

    // staging: wave w loads tile rows [w*32, w*32+32), two 16-row insts per tile
    const int rs0 = (w << 5) + (l >> 2);          // rows rs0 and rs0+16
    const int kq = ((l & 3) ^ (rs0 & 3)) << 3;    // swizzled k-offset (elements); same for rs0+16
    const ushort* gA0 = Z + (size_t)(i0 + rs0) * 256 + kq;
    const ushort* gA1 = Z + (size_t)(i0 + rs0 + 16) * 256 + kq;
    const ushort* gB0 = Z + (size_t)(j0 + rs0) * 256 + kq;
    const ushort* gB1 = Z + (size_t)(j0 + rs0 + 16) * 256 + kq;
    ushort* lA0 = lA + ((w << 5) << 5);           // wave-uniform LDS dests
    ushort* lA1 = lA + (((w << 5) + 16) << 5);
    ushort* lB0 = lB + ((w << 5) << 5);
    ushort* lB1 = lB + (((w << 5) + 16) << 5);

    // fragment LDS element offsets (swizzled), constant across chunks
    const int lane_m = l & 15, lane_q = l >> 4;
    int aoff[4], boff[4];
#pragma unroll
    for (int f = 0; f < 4; ++f) {
        const int ra = (wi << 6) + (f << 4) + lane_m;
        aoff[f] = (ra << 5) + ((lane_q ^ (ra & 3)) << 3);
        const int rb = (wj << 6) + (f << 4) + lane_m;
        boff[f] = (rb << 5) + ((lane_q ^ (rb & 3)) << 3);
    }

    floatx4 accf[4][4];
#pragma unroll
    for (int fi = 0; fi < 4; ++fi)
#pragma unroll
        for (int fj = 0; fj < 4; ++fj) accf[fi][fj] = (floatx4){0.f, 0.f, 0.f, 0.f};

    for (int ck = 0; ck < 8; ++ck) {
        __syncthreads();                           // prior chunk's reads done
        glds16(gA0, lA0); glds16(gA1, lA1);
        glds16(gB0, lB0); glds16(gB1, lB1);
        gA0 += 32; gA1 += 32; gB0 += 32; gB1 += 32;
        __syncthreads();                           // staging visible (vmcnt drained by barrier)

        short8 af[4], bfr[4];
#pragma unroll
        for (int f = 0; f < 4; ++f) {
            af[f]  = *(const short8*)(lA + aoff[f]);
            bfr[f] = *(const short8*)(lB + boff[f]);
        }
#pragma unroll
        for (int fi = 0; fi < 4; ++fi)
#pragma unroll
            for (int fj = 0; fj < 4; ++fj)
                accf[fi][fj] = __builtin_amdgcn_mfma_f32_16x16x32_bf16(af[fi], bfr[fj], accf[fi][fj], 0, 0, 0);
    }

    // ---- epilogue ----
    float negb[NSIG];
#pragma unroll
    for (int k = 0; k < NSIG; ++k) negb[k] = -0.5f / sigmas[k];

    const float* nA = norms + i0 + (wi << 6);
    const float* nB = norms + j0 + (wj << 6);
    const bool diag = (bi == bj);
    const float sgn2 = ((bi < 32) == (bj < 32)) ? 2.f : -2.f;   // off-diag pair weight (2) * sign

    float lsum = 0.f;
#pragma unroll
    for (int fi = 0; fi < 4; ++fi) {
        const floatx4 ni4 = *(const floatx4*)(nA + (fi << 4) + (lane_q << 2));
#pragma unroll
        for (int fj = 0; fj < 4; ++fj) {
            const float njs = nB[(fj << 4) + lane_m];
#pragma unroll
            for (int v = 0; v < 4; ++v) {
                float d = ni4[v] + njs - 2.f * accf[fi][fj][v];
                d = fmaxf(d, 0.f);
                float wgt;
                if (diag) {
                    const int dif = ((wi - wj) << 6) + ((fi - fj) << 4) + ((lane_q << 2) + v) - lane_m; // gi - gj
                    if (dif == 0) d = 0.f;                      // exact diagonal
                    wgt = (dif < 0) ? 2.f : ((dif == 0) ? 1.f : 0.f);
                } else {
                    wgt = 1.f;                                  // folded into sgn2 below
                }
                float ks = 0.f;
#pragma unroll
                for (int k = 0; k < NSIG; ++k) ks += __expf(negb[k] * d);
                lsum = fmaf(wgt, ks, lsum);
            }
        }
    }
    if (!diag) lsum *= sgn2;                                    // diag blocks: same-set, sign +1, weights applied

    // block reduction -> one fp64 atomic
#pragma unroll
    for (int off = 32; off > 0; off >>= 1) lsum += __shfl_down(lsum, off, 64);
    if (l == 0) wsum[w] = lsum;
    __syncthreads();
    if (t == 0) atomicAdd(acc, (double)(wsum[0] + wsum[1] + wsum[2] + wsum[3]));
}

__global__ void finalize_kernel(const double* __restrict__ acc, float* __restrict__ out) {
    out[0] = (float)(*acc * (1.0 / (4096.0 * 4096.0)));
}

extern "C" void kernel_launch(void* const* d_in, const int* in_sizes, int n_in,
                              void* d_out, int out_size, void* d_ws, size_t ws_size,
                              hipStream_t stream) {
    const float* x   = (const float*)d_in[0];
    const float* y   = (const float*)d_in[1];
    const float* sig = (const float*)d_in[2];

    __hip_bfloat16* Z = (__hip_bfloat16*)d_ws;                          // 8192*256*2 = 4 MiB
    float* norms      = (float*)((char*)d_ws + (size_t)8192 * 256 * 2); // 32 KiB
    double* acc       = (double*)((char*)norms + 8192 * sizeof(float));
    float* out        = (float*)d_out;

    prep_kernel<<<256, 256, 0, stream>>>(x, y, Z, norms, acc);
    gemm_epi<<<NBLK, 256, 0, stream>>>((const ushort*)Z, norms, sig, acc);
    finalize_kernel<<<1, 1, 0, stream>>>(acc, out);
}

// Round 3
// 112.943 us; speedup vs baseline: 3.0310x; 1.1677x over previous
//
#include <hip/hip_runtime.h>
#include <hip/hip_bf16.h>

// MMD loss via bf16 MFMA Gram matrix, exp-underflow-skipped epilogue.
// z = [xf; yf] (8192 x 256). result = (1/4096^2) * (40960 + sum_{i!=j} s_i s_j sum_k exp(-beta_k d_ij))
// Diagonal (d=0, K terms each) folded analytically into finalize.
// ws: [0,4MiB) bf16 Z[8192][256]; then float norms[8192]; then double acc.

#define NSIG 5
#define NT   64
#define NBLK ((NT * (NT + 1)) / 2)   // 2080

typedef __attribute__((ext_vector_type(8))) short short8;
typedef __attribute__((ext_vector_type(4))) float floatx4;

__device__ __forceinline__ void glds16(const ushort* g, ushort* l) {
    __builtin_amdgcn_global_load_lds((const __attribute__((address_space(1))) void*)g,
                                     (__attribute__((address_space(3))) void*)l,
                                     16, 0, 0);
}

// ---- prep: (B,C,H,W) fp32 -> Z[n][c] bf16 row-major + norms (fp32 sum of bf16^2) ----
// Block: 32 p-rows x 256 c. Thread (pl = t&31, cg = t>>5) handles 32 c's for one p.
// Loads: for fixed c, lanes pl 0..31 read 128B contiguous. Writes: 64B/lane full cachelines.
__global__ __launch_bounds__(256) void prep_kernel(const float* __restrict__ x,
                                                   const float* __restrict__ y,
                                                   ushort* __restrict__ Z,
                                                   float* __restrict__ norms,
                                                   double* __restrict__ acc) {
    const int bid = blockIdx.x;            // s(1) | b(2) | pstrip(5)
    const int t = threadIdx.x;
    if (bid == 0 && t == 0) *acc = 0.0;
    const int s = bid >> 7;
    const int rem = bid & 127;
    const int b = rem >> 5;
    const int p0 = (rem & 31) << 5;
    const float* src = s ? y : x;
    const int n0 = (s << 12) + (b << 10) + p0;

    const int pl = t & 31, cg = t >> 5;
    const float* gp = src + ((size_t)((b << 8) + (cg << 5)) << 10) + p0 + pl;

    uint pack[16];
    float nsum = 0.f;
#pragma unroll
    for (int i = 0; i < 16; ++i) {
        float f0 = gp[(size_t)(2 * i) << 10];
        float f1 = gp[(size_t)(2 * i + 1) << 10];
        __hip_bfloat16 h0 = __float2bfloat16(f0);
        __hip_bfloat16 h1 = __float2bfloat16(f1);
        float q0 = __bfloat162float(h0), q1 = __bfloat162float(h1);
        nsum = fmaf(q0, q0, nsum);
        nsum = fmaf(q1, q1, nsum);
        pack[i] = (uint)(*(ushort*)&h0) | ((uint)(*(ushort*)&h1) << 16);
    }
    uint4* zp = (uint4*)(Z + (size_t)(n0 + pl) * 256 + (cg << 5));
#pragma unroll
    for (int j = 0; j < 4; ++j)
        zp[j] = make_uint4(pack[4 * j], pack[4 * j + 1], pack[4 * j + 2], pack[4 * j + 3]);

    __shared__ float part[8][32];
    part[cg][pl] = nsum;
    __syncthreads();
    if (t < 32) {
        float v = 0.f;
#pragma unroll
        for (int g = 0; g < 8; ++g) v += part[g][t];
        norms[n0 + t] = v;
    }
}

// ---- GEMM (bf16 MFMA, double-buffered glds staging) + skip-list MMD epilogue ----
__global__ __launch_bounds__(256) void gemm_epi(const ushort* __restrict__ Z,
                                                const float* __restrict__ norms,
                                                const float* __restrict__ sigmas,
                                                double* __restrict__ acc) {
    __shared__ ushort lA[2][4096];   // [buf][128 rows x 32 k], 8KB each
    __shared__ ushort lB[2][4096];
    __shared__ float wsum[4];

    const int L = blockIdx.x;
#define TRI(b) ((b) * NT - ((b) * ((b) - 1)) / 2)
    int bi = (int)((129.0f - sqrtf((float)(129 * 129 - 8 * L))) * 0.5f);
    if (bi < 0) bi = 0;
    if (bi > NT - 1) bi = NT - 1;
    while (TRI(bi + 1) <= L) ++bi;
    while (TRI(bi) > L) --bi;
    const int bj = bi + (L - TRI(bi));

    const int i0 = bi << 7, j0 = bj << 7;
    const int t = threadIdx.x;
    const int w = t >> 6, l = t & 63;
    const int wi = w >> 1, wj = w & 1;

    // staging: wave w owns rows [w*32, w*32+32); lane l -> row rs0 = w*32 + (l>>2), LDS chunk l&3.
    // swizzle: LDS chunk c of row r holds global chunk c ^ ((r>>1)&3)  (slot-perfect, 2-way = free)
    const int rs0 = (w << 5) + (l >> 2);
    const int kq = ((l & 3) ^ ((l >> 3) & 3)) << 3;   // == (l&3) ^ ((rs0>>1)&3), in elements
    const ushort* gA0 = Z + (size_t)(i0 + rs0) * 256 + kq;
    const ushort* gA1 = gA0 + 16 * 256;
    const ushort* gB0 = Z + (size_t)(j0 + rs0) * 256 + kq;
    const ushort* gB1 = gB0 + 16 * 256;
    const int ldo0 = (w << 5) << 5;          // wave-uniform LDS element offsets
    const int ldo1 = ldo0 + (16 << 5);

    // fragment LDS offsets (swizzle-aware)
    const int lane_m = l & 15, lane_q = l >> 4;
    int aoff[4], boff[4];
#pragma unroll
    for (int f = 0; f < 4; ++f) {
        const int ra = (wi << 6) + (f << 4) + lane_m;
        aoff[f] = (ra << 5) + ((lane_q ^ ((ra >> 1) & 3)) << 3);
        const int rb = (wj << 6) + (f << 4) + lane_m;
        boff[f] = (rb << 5) + ((lane_q ^ ((rb >> 1) & 3)) << 3);
    }

    floatx4 accf[4][4];
#pragma unroll
    for (int fi = 0; fi < 4; ++fi)
#pragma unroll
        for (int fj = 0; fj < 4; ++fj) accf[fi][fj] = (floatx4){0.f, 0.f, 0.f, 0.f};

    // prefetch chunk 0 -> buf 0
    glds16(gA0, &lA[0][ldo0]); glds16(gA1, &lA[0][ldo1]);
    glds16(gB0, &lB[0][ldo0]); glds16(gB1, &lB[0][ldo1]);

    for (int ck = 0; ck < 8; ++ck) {
        const int cur = ck & 1;
        __syncthreads();                       // drains vmcnt: buf[cur] staged; buf[cur^1] reads done
        if (ck < 7) {
            const int nxt = cur ^ 1;
            const int ko = (ck + 1) << 5;
            glds16(gA0 + ko, &lA[nxt][ldo0]); glds16(gA1 + ko, &lA[nxt][ldo1]);
            glds16(gB0 + ko, &lB[nxt][ldo0]); glds16(gB1 + ko, &lB[nxt][ldo1]);
        }
        short8 af[4], bfr[4];
#pragma unroll
        for (int f = 0; f < 4; ++f) {
            af[f]  = *(const short8*)(&lA[cur][aoff[f]]);
            bfr[f] = *(const short8*)(&lB[cur][boff[f]]);
        }
#pragma unroll
        for (int fi = 0; fi < 4; ++fi)
#pragma unroll
            for (int fj = 0; fj < 4; ++fj)
                accf[fi][fj] = __builtin_amdgcn_mfma_f32_16x16x32_bf16(af[fi], bfr[fj], accf[fi][fj], 0, 0, 0);
    }

    // ---- epilogue ----
    float c2[NSIG];
#pragma unroll
    for (int k = 0; k < NSIG; ++k) c2[k] = (-0.5f / sigmas[k]) * 1.44269504f;  // log2(e)

    const float* nA = norms + i0 + (wi << 6);
    const float* nB = norms + j0 + (wj << 6);
    const bool diag = (bi == bj);
    const float sgn2 = ((bi < 32) == (bj < 32)) ? 2.f : -2.f;

    // phase A: d in place of accf; diag blocks keep only gi<gj (others -> huge d => exp 0)
#pragma unroll
    for (int fi = 0; fi < 4; ++fi) {
        const floatx4 ni4 = *(const floatx4*)(nA + (fi << 4) + (lane_q << 2));
#pragma unroll
        for (int fj = 0; fj < 4; ++fj) {
            const float njs = nB[(fj << 4) + lane_m];
#pragma unroll
            for (int v = 0; v < 4; ++v) {
                float d = fmaf(-2.f, accf[fi][fj][v], ni4[v] + njs);
                d = fmaxf(d, 0.f);
                if (diag) {
                    const int dif = ((wi - wj) << 6) + ((fi - fj) << 4) + ((lane_q << 2) + v) - lane_m;
                    d = (dif < 0) ? d : 3.0e9f;
                }
                accf[fi][fj][v] = d;
            }
        }
    }

    // phase B: wave-uniform dmin
    float dmin = accf[0][0][0];
#pragma unroll
    for (int fi = 0; fi < 4; ++fi)
#pragma unroll
        for (int fj = 0; fj < 4; ++fj)
#pragma unroll
            for (int v = 0; v < 4; ++v) dmin = fminf(dmin, accf[fi][fj][v]);
#pragma unroll
    for (int off = 1; off < 64; off <<= 1) dmin = fminf(dmin, __shfl_xor(dmin, off, 64));

    // phase C: per-k, skip if exp2 underflows for every pair in this wave (exact in fp32)
    float lsum = 0.f;
#pragma unroll
    for (int k = 0; k < NSIG; ++k) {
        if (c2[k] * dmin >= -126.f) {
#pragma unroll
            for (int fi = 0; fi < 4; ++fi)
#pragma unroll
                for (int fj = 0; fj < 4; ++fj)
#pragma unroll
                    for (int v = 0; v < 4; ++v)
                        lsum += __builtin_amdgcn_exp2f(c2[k] * accf[fi][fj][v]);
        }
    }
    lsum *= sgn2;

#pragma unroll
    for (int off = 32; off > 0; off >>= 1) lsum += __shfl_down(lsum, off, 64);
    if (l == 0) wsum[w] = lsum;
    __syncthreads();
    if (t == 0) atomicAdd(acc, (double)(wsum[0] + wsum[1] + wsum[2] + wsum[3]));
}

__global__ void finalize_kernel(const double* __restrict__ acc, float* __restrict__ out) {
    // + diagonal: 8192 rows * NSIG (exp(0) per sigma), all with s_i s_j = +1
    out[0] = (float)((*acc + 8192.0 * NSIG) * (1.0 / (4096.0 * 4096.0)));
}

extern "C" void kernel_launch(void* const* d_in, const int* in_sizes, int n_in,
                              void* d_out, int out_size, void* d_ws, size_t ws_size,
                              hipStream_t stream) {
    const float* x   = (const float*)d_in[0];
    const float* y   = (const float*)d_in[1];
    const float* sig = (const float*)d_in[2];

    ushort* Z    = (ushort*)d_ws;                                   // 4 MiB
    float* norms = (float*)((char*)d_ws + (size_t)8192 * 256 * 2);  // 32 KiB
    double* acc  = (double*)((char*)norms + 8192 * sizeof(float));
    float* out   = (float*)d_out;

    prep_kernel<<<256, 256, 0, stream>>>(x, y, Z, norms, acc);
    gemm_epi<<<NBLK, 256, 0, stream>>>(Z, norms, sig, acc);
    finalize_kernel<<<1, 1, 0, stream>>>(acc, out);
}